// Round 11
// baseline (183.529 us; speedup 1.0000x reference)
//
#include <hip/hip_runtime.h>
#include <hip/hip_bf16.h>
#include <math.h>

// B=8, Cin=Cout=128, H=W=64, K=3, S=1, P=1
// All-f16 pipeline. ws layout (total 8,757,248 B < proven-safe 10,747,904 B):
//   wT    f16 [9][128 co][128 c]  @ 0        (294,912 B)
//   woffT f16 [9][32 oc][128 c]   @ 294,912  ( 73,728 B)  oc>=18 zero
//   xT    f16 [8][64][64][128]    @ 368,640  (8,388,608 B)

typedef _Float16 f16x8 __attribute__((ext_vector_type(8)));
typedef _Float16 h2    __attribute__((ext_vector_type(2)));
typedef float    f32x4 __attribute__((ext_vector_type(4)));

// ------------------------------------------------------------------
// Kernel P: repack w / w_offset into MFMA-fragment-ready f16.
// ------------------------------------------------------------------
__global__ __launch_bounds__(256) void prep_weights(
    const float* __restrict__ w, const float* __restrict__ woff,
    _Float16* __restrict__ wT, _Float16* __restrict__ woffT) {
    int idx = blockIdx.x * 256 + threadIdx.x;
    if (idx < 147456) {
        int c  = idx & 127;
        int co = (idx >> 7) & 127;
        int kk = idx >> 14;
        wT[idx] = (_Float16)w[co * 1152 + c * 9 + kk];
    }
    if (idx < 36864) {
        int c  = idx & 127;
        int oc = (idx >> 7) & 31;
        int kk = idx >> 12;
        woffT[idx] = (oc < 18) ? (_Float16)woff[oc * 1152 + c * 9 + kk] : (_Float16)0.f;
    }
}

// ------------------------------------------------------------------
// Kernel A: NCHW fp32 -> NHWC f16 (pair-packed uint writes).
// ------------------------------------------------------------------
__global__ __launch_bounds__(256) void transpose_nchw_nhwc(
    const float* __restrict__ x, unsigned* __restrict__ xT) {
    __shared__ float tile[128][65];
    int bh = blockIdx.x;                 // b*64 + h
    int b = bh >> 6, h = bh & 63;
    const float* src = x + b * 524288 + h * 64;
    for (int idx = threadIdx.x; idx < 8192; idx += 256) {
        int c = idx >> 6, ww = idx & 63;
        tile[c][ww] = src[c * 4096 + ww];
    }
    __syncthreads();
    unsigned* dst = xT + (size_t)bh * 4096;   // [w][c/2] as uint
    for (int idx = threadIdx.x; idx < 4096; idx += 256) {
        int ww = idx >> 6, c2 = (idx & 63) * 2;
        union { h2 h; unsigned u; } p;
        p.h = h2{(_Float16)tile[c2][ww], (_Float16)tile[c2 + 1][ww]};
        dst[idx] = p.u;
    }
}

// ------------------------------------------------------------------
// Kernel C: fused deformable conv, TLP-first layout.
// Grid 1024 = (b 8) x (ho 64) x (pos-half 2); 512 thr (8 waves);
// LDS 25.6 KB -> 4 blocks/CU (4 independent barrier convoys, 32 waves/CU).
// VGPR budget <=64 (launch_bounds(512,8)) so all 32 waves are resident.
// Wave w: cout tile [w*16, w*16+16) over the block's 32 pos (2 n-frags).
// Per kk: load W(kk) (4 frags, single-buffered) then issue G(kk+1);
// compiler emits counted vmcnt: MFMA waits only W, G stays in flight,
// drained at blend(kk+1) after the MFMA cluster. 1 barrier/kk.
// Stalls are covered by the other 3 resident blocks, not by per-wave
// scheduling (R6/R7/R9 falsified that approach).
// ------------------------------------------------------------------
__global__ __launch_bounds__(512, 8) void deform_fused(
    const _Float16* __restrict__ xT,
    const _Float16* __restrict__ wT,
    const _Float16* __restrict__ woffT,
    float* __restrict__ out) {
    __shared__ unsigned short s_tile[2][4096];  // dbuf [32 pos][128 c], XOR-16B swizzle (8 KB each)
    __shared__ ushort4 s_pix[288];              // [kk][p32] pixel index (byte>>8)
    __shared__ float4  s_wt[288];               // [kk][p32] mask-folded weights
    __shared__ float   s_off[18][32];           // [oc][p32]

    int raw = blockIdx.x;
    int b    = raw & 7;                  // XCD-locality: batch == XCD
    int rest = raw >> 3;                 // 0..127
    int ho   = rest >> 1;
    int pos0 = (rest & 1) * 32;
    int t = threadIdx.x, l = t & 63, w = t >> 6;
    int lr = l & 15, lg = l >> 4;
    const char* xb = (const char*)xT + (size_t)b * 1048576;

    // ---- Phase A: offset conv (M=32 pos, N=32 oc-pad, K=1152) ----
    // 8 waves = 2m x 2n x 2dup; dup==1 recomputes (harmless), doesn't write.
    {
        int m = w & 1, n = (w >> 1) & 1, dup = w >> 2;
        f16x8 A[2][4], Bc[4];
        f32x4 oacc = {0.f, 0.f, 0.f, 0.f};
        auto loadA = [&](int kk, f16x8* dst) {
            int y  = ho + kk / 3 - 1;
            int xc = pos0 + m * 16 + lr + kk % 3 - 1;
            bool valid = ((unsigned)y < 64u) && ((unsigned)xc < 64u);
            int yc = min(max(y, 0), 63), xcc = min(max(xc, 0), 63);
            const char* p = xb + ((yc * 64 + xcc) << 8) + lg * 16;
            _Float16 mk = (_Float16)(valid ? 1.f : 0.f);
#pragma unroll
            for (int kg = 0; kg < 4; ++kg)
                dst[kg] = *(const f16x8*)(p + kg * 64) * mk;
        };
        loadA(0, A[0]);
#pragma unroll
        for (int kk = 0; kk < 9; ++kk) {
            // B first, then A(kk+1): counted vmcnt waits only B; A lands next iter.
            const _Float16* wo = woffT + ((kk * 32 + n * 16 + lr) << 7) + lg * 8;
#pragma unroll
            for (int kg = 0; kg < 4; ++kg)
                Bc[kg] = *(const f16x8*)(wo + kg * 32);
            if (kk < 8) loadA(kk + 1, A[(kk + 1) & 1]);
#pragma unroll
            for (int kg = 0; kg < 4; ++kg)
                oacc = __builtin_amdgcn_mfma_f32_16x16x32_f16(A[kk & 1][kg], Bc[kg], oacc, 0, 0, 0);
        }
        int oc = n * 16 + lr;                 // D: col = oc, row = pos
        if (dup == 0 && oc < 18) {
#pragma unroll
            for (int r = 0; r < 4; ++r)
                s_off[oc][m * 16 + lg * 4 + r] = oacc[r];
        }
    }
    __syncthreads();

    // ---- Phase B: bilinear meta, 288 = 9 kk x 32 pos ----
    if (t < 288) {
        int p32 = t & 31, kk = t >> 5;
        float dy = s_off[2 * kk][p32], dx = s_off[2 * kk + 1][p32];
        float py = (float)(ho + kk / 3 - 1) + dy;
        float px = (float)(pos0 + p32 + kk % 3 - 1) + dx;
        float y0f = floorf(py), x0f = floorf(px);
        float ly = py - y0f, lx = px - x0f;
        int y0 = (int)y0f, x0 = (int)x0f;
        int y1 = y0 + 1, x1 = x0 + 1;
        float my0 = ((unsigned)y0 < 64u) ? 1.f : 0.f;
        float my1 = ((unsigned)y1 < 64u) ? 1.f : 0.f;
        float mx0 = ((unsigned)x0 < 64u) ? 1.f : 0.f;
        float mx1 = ((unsigned)x1 < 64u) ? 1.f : 0.f;
        int y0c = min(max(y0, 0), 63), y1c = min(max(y1, 0), 63);
        int x0c = min(max(x0, 0), 63), x1c = min(max(x1, 0), 63);
        s_pix[t] = make_ushort4((unsigned short)(y0c * 64 + x0c),
                                (unsigned short)(y0c * 64 + x1c),
                                (unsigned short)(y1c * 64 + x0c),
                                (unsigned short)(y1c * 64 + x1c));
        s_wt[t] = make_float4((1.f - ly) * (1.f - lx) * my0 * mx0,
                              (1.f - ly) * lx * my0 * mx1,
                              ly * (1.f - lx) * my1 * mx0,
                              ly * lx * my1 * mx1);
    }
    __syncthreads();

    // ---- Main loop ----
    int p32 = t >> 4;         // thread's pos (0..31)
    int cq  = t & 15;         // 16B column within the 256B pixel row
    int cb  = w * 16;         // wave's cout base
    f32x4 acc[2] = {{0.f,0.f,0.f,0.f},{0.f,0.f,0.f,0.f}};
    uint4 u[4];               // in-flight corner gathers (16B each)

    auto issueG = [&](int kk) {
        ushort4 pc = s_pix[kk * 32 + p32];
        const char* bb = xb + cq * 16;
        u[0] = *(const uint4*)(bb + ((int)pc.x << 8));
        u[1] = *(const uint4*)(bb + ((int)pc.y << 8));
        u[2] = *(const uint4*)(bb + ((int)pc.z << 8));
        u[3] = *(const uint4*)(bb + ((int)pc.w << 8));
    };
    auto blend = [&](int kk, int buf) {
        float4 wt = s_wt[kk * 32 + p32];
        h2 w0 = h2{(_Float16)wt.x, (_Float16)wt.x};
        h2 w1 = h2{(_Float16)wt.y, (_Float16)wt.y};
        h2 w2 = h2{(_Float16)wt.z, (_Float16)wt.z};
        h2 w3 = h2{(_Float16)wt.w, (_Float16)wt.w};
        union { uint4 q; h2 h[4]; } c0, c1, c2, c3, r;
        c0.q = u[0]; c1.q = u[1]; c2.q = u[2]; c3.q = u[3];
#pragma unroll
        for (int j = 0; j < 4; ++j)
            r.h[j] = w0 * c0.h[j] + w1 * c1.h[j] + w2 * c2.h[j] + w3 * c3.h[j];
        char* tpb = (char*)s_tile[buf];
        *(uint4*)(tpb + p32 * 256 + ((cq ^ (p32 & 15)) << 4)) = r.q;
    };

    // prologue: gathers(0) -> tile[0]
    issueG(0);
    blend(0, 0);
    __syncthreads();

#pragma unroll
    for (int kk = 0; kk < 9; ++kk) {
        // W(kk) first, G(kk+1) second: vmcnt before MFMA is counted (waits W only)
        f16x8 Wf[4];
        const _Float16* wr = wT + ((kk * 128 + cb + lr) << 7) + lg * 8;
#pragma unroll
        for (int kg = 0; kg < 4; ++kg)
            Wf[kg] = *(const f16x8*)(wr + kg * 32);
        __builtin_amdgcn_sched_barrier(0);
        if (kk < 8) issueG(kk + 1);
        __builtin_amdgcn_sched_barrier(0);
        {
            char* rp = (char*)s_tile[kk & 1];
#pragma unroll
            for (int kg = 0; kg < 4; ++kg) {
                int slot = kg * 4 + lg;
#pragma unroll
                for (int n = 0; n < 2; ++n) {
                    int row = n * 16 + lr;
                    f16x8 Bf = *(const f16x8*)(rp + row * 256 + ((slot ^ (row & 15)) << 4));
                    acc[n] = __builtin_amdgcn_mfma_f32_16x16x32_f16(Wf[kg], Bf, acc[n], 0, 0, 0);
                }
            }
        }
        __builtin_amdgcn_sched_barrier(0);
        if (kk < 8) blend(kk + 1, (kk + 1) & 1);   // vmcnt(0) for G lands here
        __syncthreads();
    }

    // Epilogue: cout = cb + lg*4 + r, pos = pos0 + n*16 + lr
    float* ob = out + ((size_t)(b * 128 + cb + lg * 4)) * 4096 + ho * 64 + pos0;
#pragma unroll
    for (int n = 0; n < 2; ++n) {
#pragma unroll
        for (int r = 0; r < 4; ++r)
            ob[r * 4096 + n * 16 + lr] = acc[n][r];
    }
}

// ------------------------------------------------------------------
extern "C" void kernel_launch(void* const* d_in, const int* in_sizes, int n_in,
                              void* d_out, int out_size, void* d_ws, size_t ws_size,
                              hipStream_t stream) {
    const float* x    = (const float*)d_in[0];
    const float* woff = (const float*)d_in[1];
    const float* w    = (const float*)d_in[2];
    float* out = (float*)d_out;

    _Float16* wT    = (_Float16*)d_ws;                     // 294,912 B
    _Float16* woffT = (_Float16*)((char*)d_ws + 294912);   //  73,728 B
    _Float16* xT    = (_Float16*)((char*)d_ws + 368640);   // 8,388,608 B

    prep_weights<<<576, 256, 0, stream>>>(w, woff, wT, woffT);
    transpose_nchw_nhwc<<<512, 256, 0, stream>>>(x, (unsigned*)xT);
    deform_fused<<<1024, 512, 0, stream>>>(xT, wT, woffT, out);
}